// Round 1
// baseline (765.503 us; speedup 1.0000x reference)
//
#include <hip/hip_runtime.h>

#define N_PATHS 8192
#define T_STEPS 256
#define D_IN    44
#define H_SZ    8
#define G4      32      // 4*H
#define NGROUPS 1024
#define TC      16      // timesteps per chunk

// ---------------- workspace layout (floats) ----------------
// [0, 1408)            Wt   : W_ih transposed+gate-permuted [d][u*4+m]
// [1408, 1440)         bias : b_ih + b_hh (gate-permuted)
// [1440, 1440+8192)    perm : path ids sorted by last_idx (int)
// [9632, 9632+8192)    s    : per-path score dot(h_last, fc_W)

__device__ __forceinline__ float sigm_f(float x) {
    return __builtin_amdgcn_rcpf(1.0f + __expf(-x));
}
__device__ __forceinline__ float tanh_f(float x) {
    return 1.0f - 2.0f * __builtin_amdgcn_rcpf(1.0f + __expf(2.0f * x));
}

// quad_perm DPP: ctrl 0xB1 = [1,0,3,2] (lane^1), 0x4E = [2,3,0,1] (lane^2)
template <int CTRL>
__device__ __forceinline__ float dpp_qp(float v) {
    int i = __builtin_bit_cast(int, v);
    i = __builtin_amdgcn_update_dpp(0, i, CTRL, 0xF, 0xF, true);
    return __builtin_bit_cast(float, i);
}
// ds_swizzle xor-mode: offset = (xor<<10)|(or<<5)|and ; lane^4 = 0x101F
__device__ __forceinline__ float swz_xor4(float v) {
    int i = __builtin_bit_cast(int, v);
    i = __builtin_amdgcn_ds_swizzle(i, 0x101F);
    return __builtin_bit_cast(float, i);
}

// ---------------- prep: permuted transpose + counting sort by last_idx ----------------
__global__ void prep_kernel(const float* __restrict__ W_ih, const float* __restrict__ b_ih,
                            const float* __restrict__ b_hh, const int* __restrict__ last_idx,
                            float* __restrict__ Wt, float* __restrict__ bias,
                            int* __restrict__ perm) {
    __shared__ int hist[256];
    __shared__ int off[256];
    const int tid = threadIdx.x;  // 256 threads
    hist[tid] = 0;
    // transpose W_ih [32][44] -> Wt [44][32], gate index permuted to unit-major:
    // row g = m*8+u  ->  column u*4+m  (so phase-2 reads one float4 per (path,unit))
    for (int idx = tid; idx < G4 * D_IN; idx += 256) {
        int g = idx / D_IN, d = idx - g * D_IN;
        int gp = ((g & 7) << 2) | (g >> 3);   // u*4 + m
        Wt[d * G4 + gp] = W_ih[idx];
    }
    if (tid < G4) {
        int gp = ((tid & 7) << 2) | (tid >> 3);
        bias[gp] = b_ih[tid] + b_hh[tid];
    }
    __syncthreads();
    for (int k = 0; k < N_PATHS / 256; ++k)
        atomicAdd(&hist[last_idx[k * 256 + tid]], 1);
    __syncthreads();
    if (tid == 0) {  // serial exclusive scan over 256 bins: trivial cost
        int run = 0;
        for (int i = 0; i < 256; ++i) { off[i] = run; run += hist[i]; }
    }
    __syncthreads();
    for (int k = 0; k < N_PATHS / 256; ++k) {
        int p = k * 256 + tid;
        int b = last_idx[p];
        int pos = atomicAdd(&off[b], 1);
        perm[pos] = p;   // order within a length-bin is arbitrary; harmless
    }
}

// ---------------- main fused LSTM kernel ----------------
// 1 wave per block, 4 length-sorted paths per wave, no __syncthreads needed.
// Phase 1 (64 lanes = 4 paths x 16 t): xg GEMM, SGPR-streamed weights -> LDS.
//   x loads for chunk ch+1 are issued before phase 2 of chunk ch (HBM latency
//   hides under the recurrence even at 1 resident wave/SIMD).
// Phase 2 (32 lanes = 4 paths x 8 units): recurrence. h is exchanged fully
//   in-register: quad_perm DPP (lane^1, lane^2) + ds_swizzle (lane^4) allgather,
//   with whh's k-index pre-permuted per lane (k = j^p). No LDS in the chain.
__global__ __launch_bounds__(64, 2)
void lstm_kernel(const float* __restrict__ x, const float* __restrict__ Whh,
                 const float* __restrict__ Wt, const float* __restrict__ bias,
                 const float* __restrict__ fcW, const int* __restrict__ last_idx,
                 const int* __restrict__ perm, float* __restrict__ sout) {
    // xg2[tc][pl*40 + u*4 + m]: pl stride 40 == 8 mod 32 -> conflict-light both ways.
    __shared__ float xg2[TC][160];   // 10.2 KB

    const int lane = threadIdx.x;
    const int b = blockIdx.x;  // 0..2047, sorted segments

    // uniform (scalar) path metadata
    const int p0 = perm[4 * b + 0], p1 = perm[4 * b + 1];
    const int p2 = perm[4 * b + 2], p3 = perm[4 * b + 3];
    const int l0 = last_idx[p0], l1 = last_idx[p1];
    const int l2 = last_idx[p2], l3 = last_idx[p3];
    const int wmax = max(max(l0, l1), max(l2, l3));

    // phase-1 ids: lane = tc*4 + pl
    const int pl1 = lane & 3, tc1 = lane >> 2;
    // phase-2 ids
    const int pl2 = lane >> 3, j = lane & 7;
    const bool act2 = lane < 32;

    const int pg1 = pl1 == 0 ? p0 : pl1 == 1 ? p1 : pl1 == 2 ? p2 : p3;
    const int pg2 = pl2 == 0 ? p0 : pl2 == 1 ? p1 : pl2 == 2 ? p2 : p3;
    const int lst2 = pl2 == 0 ? l0 : pl2 == 1 ? l1 : pl2 == 2 ? l2 : l3;

    // W_hh rows {j, 8+j, 16+j, 24+j}, k-index permuted so whh[m][p] pairs with
    // r[p] = h_{j^p} from the allgather.
    float whh[4][8];
#pragma unroll
    for (int m = 0; m < 4; ++m)
#pragma unroll
        for (int p = 0; p < 8; ++p)
            whh[m][p] = Whh[(m * 8 + j) * H_SZ + (j ^ p)];
    const float fcWj = fcW[j];

    float hval = 0.f, cval = 0.f, hlast = 0.f;

    const float* xrow_base = x + (size_t)pg1 * (T_STEPS * D_IN);
    const int nch = (wmax >> 4) + 1;  // truncate at per-wave max length

    // software pipeline: preload chunk 0's x row into registers
    float4 xv[11];
    {
        const float4* xr = (const float4*)(xrow_base + tc1 * D_IN);
#pragma unroll
        for (int q = 0; q < 11; ++q) xv[q] = xr[q];
    }

    for (int ch = 0; ch < nch; ++ch) {
        // ---------------- phase 1: xg = bias + x . Wt ----------------
        {
            float acc[32];
#pragma unroll
            for (int g = 0; g < 32; ++g) acc[g] = bias[g];   // uniform -> SGPR
#pragma unroll
            for (int q = 0; q < 11; ++q) {
                float4 v = xv[q];
#pragma unroll
                for (int r = 0; r < 4; ++r) {
                    const float xd = (r == 0) ? v.x : (r == 1) ? v.y : (r == 2) ? v.z : v.w;
                    const int d = 4 * q + r;
#pragma unroll
                    for (int g = 0; g < 32; ++g)
                        acc[g] = fmaf(Wt[d * 32 + g], xd, acc[g]);  // Wt uniform -> s_load stream
                }
            }
#pragma unroll
            for (int k = 0; k < 8; ++k) {
                float4 v = make_float4(acc[4 * k], acc[4 * k + 1], acc[4 * k + 2], acc[4 * k + 3]);
                *(float4*)&xg2[tc1][pl1 * 40 + 4 * k] = v;
            }
        }
        // preload next chunk's x into registers; consumed next iteration, so the
        // ~900-cycle HBM latency hides under phase 2 below. (uniform branch)
        if (ch + 1 < nch) {
            const float4* xr = (const float4*)(xrow_base + ((ch + 1) * TC + tc1) * D_IN);
#pragma unroll
            for (int q = 0; q < 11; ++q) xv[q] = xr[q];
        }
        // ---------------- phase 2: 16 recurrence steps ----------------
        if (act2) {
            const int t0 = ch * TC;
#pragma unroll
            for (int tt = 0; tt < TC; ++tt) {
                // one b128: (i,f,g,o) pre-acts for this (path,unit); independent of
                // the recurrence -> compiler hoists these early across steps
                const float4 xg = *(const float4*)&xg2[tt][pl2 * 40 + 4 * j];
                // in-register allgather of h across the 8-lane group: r[p] = h_{j^p}
                const float r0 = hval;
                const float r1 = dpp_qp<0xB1>(r0);   // lane^1
                const float r2 = dpp_qp<0x4E>(r0);   // lane^2
                const float r3 = dpp_qp<0x4E>(r1);
                const float r4 = swz_xor4(r0);       // lane^4
                const float r5 = swz_xor4(r1);
                const float r6 = swz_xor4(r2);
                const float r7 = swz_xor4(r3);
                float pre[4];
                const float xgc[4] = {xg.x, xg.y, xg.z, xg.w};
#pragma unroll
                for (int m = 0; m < 4; ++m) {
                    // two 4-deep chains + combine: shorter critical path than 8-deep
                    float pa = fmaf(whh[m][0], r0, xgc[m]);
                    pa = fmaf(whh[m][1], r1, pa);
                    pa = fmaf(whh[m][2], r2, pa);
                    pa = fmaf(whh[m][3], r3, pa);
                    float pb = whh[m][4] * r4;
                    pb = fmaf(whh[m][5], r5, pb);
                    pb = fmaf(whh[m][6], r6, pb);
                    pb = fmaf(whh[m][7], r7, pb);
                    pre[m] = pa + pb;
                }
                const float ig = sigm_f(pre[0]);
                const float fg = sigm_f(pre[1]);
                const float gg = tanh_f(pre[2]);
                const float og = sigm_f(pre[3]);
                cval = fmaf(fg, cval, ig * gg);
                hval = og * tanh_f(cval);
                const int t = t0 + tt;
                hlast = (t == lst2) ? hval : hlast;
            }
        }
    }

    if (act2) {
        float v = hlast * fcWj;            // per-path score = dot(h_last, fc_W)
        v += __shfl_xor(v, 1);
        v += __shfl_xor(v, 2);
        v += __shfl_xor(v, 4);
        if (j == 0) sout[pg2] = v;
    }
}

// ---------------- finalize: segment-sum + softmax over 1024 groups ----------------
__global__ void finalize_kernel(const float* __restrict__ s, const int* __restrict__ gid,
                                float* __restrict__ out) {
    __shared__ float seg[NGROUPS];
    __shared__ float red[16];
    const int tid = threadIdx.x;  // 1024
    seg[tid] = 0.f;
    __syncthreads();
#pragma unroll
    for (int k = 0; k < 8; ++k) {
        const int p = k * 1024 + tid;
        atomicAdd(&seg[gid[p]], s[p]);
    }
    __syncthreads();
    const float v = seg[tid];  // logit (fc_b cancels exactly in softmax)
    const int wid = tid >> 6, ln = tid & 63;
    // ---- max reduce ----
    float m = v;
#pragma unroll
    for (int o = 32; o >= 1; o >>= 1) m = fmaxf(m, __shfl_xor(m, o));
    if (ln == 0) red[wid] = m;
    __syncthreads();
    if (tid < 16) {
        float mm = red[tid];
#pragma unroll
        for (int o = 8; o >= 1; o >>= 1) mm = fmaxf(mm, __shfl_xor(mm, o));
        red[tid] = mm;
    }
    __syncthreads();
    const float vmax = red[0];
    __syncthreads();  // protect red[] reuse
    // ---- sum reduce ----
    const float e = __expf(v - vmax);
    float ss = e;
#pragma unroll
    for (int o = 32; o >= 1; o >>= 1) ss += __shfl_xor(ss, o);
    if (ln == 0) red[wid] = ss;
    __syncthreads();
    if (tid < 16) {
        float s2 = red[tid];
#pragma unroll
        for (int o = 8; o >= 1; o >>= 1) s2 += __shfl_xor(s2, o);
        red[tid] = s2;
    }
    __syncthreads();
    const float tot = red[0];
    out[tid] = e / tot;
}

extern "C" void kernel_launch(void* const* d_in, const int* in_sizes, int n_in,
                              void* d_out, int out_size, void* d_ws, size_t ws_size,
                              hipStream_t stream) {
    const float* x      = (const float*)d_in[0];
    const float* W_ih   = (const float*)d_in[1];
    const float* W_hh   = (const float*)d_in[2];
    const float* b_ih   = (const float*)d_in[3];
    const float* b_hh   = (const float*)d_in[4];
    const float* fcW    = (const float*)d_in[5];
    // d_in[6] = fc_b: constant shift of all logits -> cancels in softmax, skipped
    const int* last_idx = (const int*)d_in[7];
    const int* gid      = (const int*)d_in[8];

    float* wsf  = (float*)d_ws;
    float* Wt   = wsf;
    float* bias = wsf + 1408;
    int*   perm = (int*)(wsf + 1440);
    float* sarr = wsf + 1440 + 8192;
    float* out  = (float*)d_out;

    hipLaunchKernelGGL(prep_kernel, dim3(1), dim3(256), 0, stream,
                       W_ih, b_ih, b_hh, last_idx, Wt, bias, perm);
    hipLaunchKernelGGL(lstm_kernel, dim3(N_PATHS / 4), dim3(64), 0, stream,
                       x, W_hh, Wt, bias, fcW, last_idx, perm, sarr);
    hipLaunchKernelGGL(finalize_kernel, dim3(1), dim3(1024), 0, stream,
                       sarr, gid, out);
}

// Round 3
// 707.615 us; speedup vs baseline: 1.0818x; 1.0818x over previous
//
#include <hip/hip_runtime.h>

#define N_PATHS 8192
#define T_STEPS 256
#define D_IN    44
#define H_SZ    8
#define G4      32      // 4*H
#define NGROUPS 1024
#define TC      16      // timesteps per chunk

// ---------------- workspace layout (floats) ----------------
// [0, 1408)            Wt   : W_ih transposed+gate-permuted [d][u*4+m]
// [1408, 1440)         bias : b_ih + b_hh (gate-permuted)
// [1440, 1440+8192)    perm : path ids sorted by last_idx (int)
// [9632, 9632+8192)    s    : per-path score dot(h_last, fc_W)

__device__ __forceinline__ float sigm_f(float x) {
    return __builtin_amdgcn_rcpf(1.0f + __expf(-x));
}
__device__ __forceinline__ float tanh_f(float x) {
    return 1.0f - 2.0f * __builtin_amdgcn_rcpf(1.0f + __expf(2.0f * x));
}

// ---------------- prep: permuted transpose + counting sort by last_idx ----------------
__global__ void prep_kernel(const float* __restrict__ W_ih, const float* __restrict__ b_ih,
                            const float* __restrict__ b_hh, const int* __restrict__ last_idx,
                            float* __restrict__ Wt, float* __restrict__ bias,
                            int* __restrict__ perm) {
    __shared__ int hist[256];
    __shared__ int off[256];
    const int tid = threadIdx.x;  // 256 threads
    hist[tid] = 0;
    // transpose W_ih [32][44] -> Wt [44][32], gate index permuted to unit-major:
    // row g = m*8+u  ->  column u*4+m  (so phase-2 reads one float4 per (path,unit))
    for (int idx = tid; idx < G4 * D_IN; idx += 256) {
        int g = idx / D_IN, d = idx - g * D_IN;
        int gp = ((g & 7) << 2) | (g >> 3);   // u*4 + m
        Wt[d * G4 + gp] = W_ih[idx];
    }
    if (tid < G4) {
        int gp = ((tid & 7) << 2) | (tid >> 3);
        bias[gp] = b_ih[tid] + b_hh[tid];
    }
    __syncthreads();
    for (int k = 0; k < N_PATHS / 256; ++k)
        atomicAdd(&hist[last_idx[k * 256 + tid]], 1);
    __syncthreads();
    if (tid == 0) {  // serial exclusive scan over 256 bins: trivial cost
        int run = 0;
        for (int i = 0; i < 256; ++i) { off[i] = run; run += hist[i]; }
    }
    __syncthreads();
    for (int k = 0; k < N_PATHS / 256; ++k) {
        int p = k * 256 + tid;
        int b = last_idx[p];
        int pos = atomicAdd(&off[b], 1);
        perm[pos] = p;   // order within a length-bin is arbitrary; harmless
    }
}

// ---------------- main fused LSTM kernel ----------------
// 1 wave per block, 4 length-sorted paths per wave, no __syncthreads needed.
// __launch_bounds__(64, 1): VGPR cap 512 so the full working set
// (acc[32] + xv[44] + whh[32] + state) stays register-resident — round-0/1
// showed ~9 MB of scratch WRITE_SIZE at the (64,2)/VGPR-84 setting, i.e. the
// compiler was spilling weights into the serial recurrence chain.
// Blocks are processed LONGEST-FIRST (perm is sorted ascending by length;
// b = 2047 - blockIdx.x) so the long chains start at t=0 and short blocks
// backfill — shrinks the tail that held average occupancy at ~1 wave/SIMD.
__global__ __launch_bounds__(64, 1)
void lstm_kernel(const float* __restrict__ x, const float* __restrict__ Whh,
                 const float* __restrict__ Wt, const float* __restrict__ bias,
                 const float* __restrict__ fcW, const int* __restrict__ last_idx,
                 const int* __restrict__ perm, float* __restrict__ sout) {
    // xg2[tc][pl*40 + u*4 + m]: pl stride 40 == 8 mod 32 -> conflict-light both ways.
    __shared__ float xg2[TC][160];                 // 10.2 KB
    __shared__ __align__(16) float hbuf[4][12];    // 12-pad: float4-aligned rows

    const int lane = threadIdx.x;
    const int b = (N_PATHS / 4 - 1) - blockIdx.x;  // longest-first (LPT)

    // uniform (scalar) path metadata
    const int p0 = perm[4 * b + 0], p1 = perm[4 * b + 1];
    const int p2 = perm[4 * b + 2], p3 = perm[4 * b + 3];
    const int l0 = last_idx[p0], l1 = last_idx[p1];
    const int l2 = last_idx[p2], l3 = last_idx[p3];
    const int wmax = max(max(l0, l1), max(l2, l3));

    // phase-1 ids: lane = tc*4 + pl  (keeps LDS write octets conflict-light)
    const int pl1 = lane & 3, tc1 = lane >> 2;
    // phase-2 ids
    const int pl2 = lane >> 3, j = lane & 7;
    const bool act2 = lane < 32;

    const int pg1 = pl1 == 0 ? p0 : pl1 == 1 ? p1 : pl1 == 2 ? p2 : p3;
    const int pg2 = pl2 == 0 ? p0 : pl2 == 1 ? p1 : pl2 == 2 ? p2 : p3;
    const int lst2 = pl2 == 0 ? l0 : pl2 == 1 ? l1 : pl2 == 2 ? l2 : l3;

    // preload W_hh rows {j, 8+j, 16+j, 24+j} -> 32 VGPRs (straight k-order)
    float whh[4][8];
#pragma unroll
    for (int m = 0; m < 4; ++m) {
        const float4* r = (const float4*)(Whh + (m * 8 + j) * H_SZ);
        float4 a = r[0], c = r[1];
        whh[m][0] = a.x; whh[m][1] = a.y; whh[m][2] = a.z; whh[m][3] = a.w;
        whh[m][4] = c.x; whh[m][5] = c.y; whh[m][6] = c.z; whh[m][7] = c.w;
    }
    const float fcWj = fcW[j];

    float hval = 0.f, cval = 0.f, hlast = 0.f;
    if (act2) hbuf[pl2][j] = 0.f;   // h0 = 0 (read before first write in phase 2)

    const float* xrow_base = x + (size_t)pg1 * (T_STEPS * D_IN);
    const int nch = (wmax >> 4) + 1;  // truncate at per-wave max length

    // software pipeline: preload chunk 0's x row into registers
    float4 xv[11];
    {
        const float4* xr = (const float4*)(xrow_base + tc1 * D_IN);
#pragma unroll
        for (int q = 0; q < 11; ++q) xv[q] = xr[q];
    }

    for (int ch = 0; ch < nch; ++ch) {
        // ---------------- phase 1: xg = bias + x . Wt ----------------
        {
            float acc[32];
#pragma unroll
            for (int g = 0; g < 32; ++g) acc[g] = bias[g];   // uniform -> SGPR, hoisted
#pragma unroll
            for (int q = 0; q < 11; ++q) {
                float4 v = xv[q];
#pragma unroll
                for (int r = 0; r < 4; ++r) {
                    const float xd = (r == 0) ? v.x : (r == 1) ? v.y : (r == 2) ? v.z : v.w;
                    const int d = 4 * q + r;
#pragma unroll
                    for (int g = 0; g < 32; ++g)
                        acc[g] = fmaf(Wt[d * 32 + g], xd, acc[g]);  // Wt uniform -> s_load stream (sL1-hot)
                }
            }
#pragma unroll
            for (int k = 0; k < 8; ++k) {
                float4 v = make_float4(acc[4 * k], acc[4 * k + 1], acc[4 * k + 2], acc[4 * k + 3]);
                *(float4*)&xg2[tc1][pl1 * 40 + 4 * k] = v;
            }
        }
        // preload next chunk's x into registers; consumed next iteration, so the
        // HBM latency hides under phase 2 below. (uniform branch)
        if (ch + 1 < nch) {
            const float4* xr = (const float4*)(xrow_base + ((ch + 1) * TC + tc1) * D_IN);
#pragma unroll
            for (int q = 0; q < 11; ++q) xv[q] = xr[q];
        }
        // ---------------- phase 2: 16 recurrence steps ----------------
        if (act2) {
            const int t0 = ch * TC;
#pragma unroll
            for (int tt = 0; tt < TC; ++tt) {
                // one b128: (i,f,g,o) pre-acts for this (path,unit); independent of
                // the recurrence -> compiler hoists these early across steps
                const float4 xg = *(const float4*)&xg2[tt][pl2 * 40 + 4 * j];
                const float4 h01 = *(const float4*)&hbuf[pl2][0];
                const float4 h23 = *(const float4*)&hbuf[pl2][4];
                const float xgc[4] = {xg.x, xg.y, xg.z, xg.w};
                float pre[4];
#pragma unroll
                for (int m = 0; m < 4; ++m) {
                    float p = xgc[m];
                    p = fmaf(whh[m][0], h01.x, p); p = fmaf(whh[m][1], h01.y, p);
                    p = fmaf(whh[m][2], h01.z, p); p = fmaf(whh[m][3], h01.w, p);
                    p = fmaf(whh[m][4], h23.x, p); p = fmaf(whh[m][5], h23.y, p);
                    p = fmaf(whh[m][6], h23.z, p); p = fmaf(whh[m][7], h23.w, p);
                    pre[m] = p;
                }
                const float ig = sigm_f(pre[0]);
                const float fg = sigm_f(pre[1]);
                const float gg = tanh_f(pre[2]);
                const float og = sigm_f(pre[3]);
                cval = fmaf(fg, cval, ig * gg);
                hval = og * tanh_f(cval);
                const int t = t0 + tt;
                hlast = (t == lst2) ? hval : hlast;
                hbuf[pl2][j] = hval;   // same-wave LDS: in-order, no barrier needed
            }
        }
    }

    if (act2) {
        float v = hlast * fcWj;            // per-path score = dot(h_last, fc_W)
        v += __shfl_xor(v, 1);
        v += __shfl_xor(v, 2);
        v += __shfl_xor(v, 4);
        if (j == 0) sout[pg2] = v;
    }
}

// ---------------- finalize: segment-sum + softmax over 1024 groups ----------------
__global__ void finalize_kernel(const float* __restrict__ s, const int* __restrict__ gid,
                                float* __restrict__ out) {
    __shared__ float seg[NGROUPS];
    __shared__ float red[16];
    const int tid = threadIdx.x;  // 1024
    seg[tid] = 0.f;
    __syncthreads();
#pragma unroll
    for (int k = 0; k < 8; ++k) {
        const int p = k * 1024 + tid;
        atomicAdd(&seg[gid[p]], s[p]);
    }
    __syncthreads();
    const float v = seg[tid];  // logit (fc_b cancels exactly in softmax)
    const int wid = tid >> 6, ln = tid & 63;
    // ---- max reduce ----
    float m = v;
#pragma unroll
    for (int o = 32; o >= 1; o >>= 1) m = fmaxf(m, __shfl_xor(m, o));
    if (ln == 0) red[wid] = m;
    __syncthreads();
    if (tid < 16) {
        float mm = red[tid];
#pragma unroll
        for (int o = 8; o >= 1; o >>= 1) mm = fmaxf(mm, __shfl_xor(mm, o));
        red[tid] = mm;
    }
    __syncthreads();
    const float vmax = red[0];
    __syncthreads();  // protect red[] reuse
    // ---- sum reduce ----
    const float e = __expf(v - vmax);
    float ss = e;
#pragma unroll
    for (int o = 32; o >= 1; o >>= 1) ss += __shfl_xor(ss, o);
    if (ln == 0) red[wid] = ss;
    __syncthreads();
    if (tid < 16) {
        float s2 = red[tid];
#pragma unroll
        for (int o = 8; o >= 1; o >>= 1) s2 += __shfl_xor(s2, o);
        red[tid] = s2;
    }
    __syncthreads();
    const float tot = red[0];
    out[tid] = e / tot;
}

extern "C" void kernel_launch(void* const* d_in, const int* in_sizes, int n_in,
                              void* d_out, int out_size, void* d_ws, size_t ws_size,
                              hipStream_t stream) {
    const float* x      = (const float*)d_in[0];
    const float* W_ih   = (const float*)d_in[1];
    const float* W_hh   = (const float*)d_in[2];
    const float* b_ih   = (const float*)d_in[3];
    const float* b_hh   = (const float*)d_in[4];
    const float* fcW    = (const float*)d_in[5];
    // d_in[6] = fc_b: constant shift of all logits -> cancels in softmax, skipped
    const int* last_idx = (const int*)d_in[7];
    const int* gid      = (const int*)d_in[8];

    float* wsf  = (float*)d_ws;
    float* Wt   = wsf;
    float* bias = wsf + 1408;
    int*   perm = (int*)(wsf + 1440);
    float* sarr = wsf + 1440 + 8192;
    float* out  = (float*)d_out;

    hipLaunchKernelGGL(prep_kernel, dim3(1), dim3(256), 0, stream,
                       W_ih, b_ih, b_hh, last_idx, Wt, bias, perm);
    hipLaunchKernelGGL(lstm_kernel, dim3(N_PATHS / 4), dim3(64), 0, stream,
                       x, W_hh, Wt, bias, fcW, last_idx, perm, sarr);
    hipLaunchKernelGGL(finalize_kernel, dim3(1), dim3(1024), 0, stream,
                       sarr, gid, out);
}